// Round 1
// baseline (1050.342 us; speedup 1.0000x reference)
//
#include <hip/hip_runtime.h>

// Correlation / cost volume:
// corr[n, dy*9+dx, h, w] = sum_c f0[n,c,h,w] * f1[n,c,h+dy-4,w+dx-4] (0-padded)
// N=8, C=256, H=W=128, MAX_DISP=4 -> D=9, 81 disp channels.
//
// Block = 576 threads = 9 waves; wave w handles dy=w. Lane -> (ty 0..31, tx 0..1).
// Tile: 32 rows x 16 cols of output pixels; thread computes 8 px x 9 dx = 72 accs.
// fmap1 halo tile (40 rows x 24 cols) staged in LDS per 8-channel chunk,
// XOR-swizzled at 16B granularity (row stride 128B) for conflict-free ds_read_b128.

#define CCH 8        // channels per LDS chunk
#define TH  32       // tile rows
#define TWp 16       // tile cols
#define PX  8        // pixels per thread (along w)
#define DD  9        // displacement count per axis
#define HR  40       // halo rows  = TH + 8
#define HCOL 24      // halo cols  = TWp + 8
#define LSTR 32      // LDS row stride in floats (128 B)
#define Cc  256
#define Hh  128
#define Ww  128

__global__ __launch_bounds__(576, 3)
void corr_kernel(const float* __restrict__ f0,
                 const float* __restrict__ f1,
                 float* __restrict__ out) {
    const int tid  = threadIdx.x;
    const int wave = tid >> 6;        // dy in [0,9)
    const int lane = tid & 63;
    const int ty   = lane >> 1;       // 0..31 (output row within tile)
    const int tx   = lane & 1;        // 0..1  (8-px group)

    const int bid = blockIdx.x;
    const int n   = bid >> 5;         // 8 images
    const int hb  = (bid >> 3) & 3;   // 4 h-tiles
    const int wb  = bid & 7;          // 8 w-tiles
    const int h0  = hb * TH;
    const int w0  = wb * TWp;

    __shared__ float lds[CCH][HR][LSTR];   // 40 KB

    // staging decomposition: 576 threads = 24 j x 24 r-slots
    const int sj  = tid % 24;              // halo col
    const int srq = tid / 24;              // base halo row slot

    const float* f1n    = f1 + (size_t)n * Cc * Hh * Ww;
    const float* f0base = f0 + ((size_t)(n * Cc) * Hh + (h0 + ty)) * Ww + w0 + PX * tx;

    float acc[DD][PX];
#pragma unroll
    for (int d = 0; d < DD; ++d)
#pragma unroll
        for (int p = 0; p < PX; ++p) acc[d][p] = 0.f;

    float stg[CCH][2];

    // hoistable per-thread staging geometry
    const int gh0 = h0 - 4;
    const int gw  = w0 - 4 + sj;
    const bool wok = ((unsigned)gw < (unsigned)Ww);

#define LOAD_CHUNK(C0)                                                         \
    {                                                                          \
        _Pragma("unroll")                                                      \
        for (int c = 0; c < CCH; ++c) {                                        \
            _Pragma("unroll")                                                  \
            for (int s = 0; s < 2; ++s) {                                      \
                const int r  = srq + 24 * s;                                   \
                const int gh = gh0 + r;                                        \
                const bool inb = (r < HR) && ((unsigned)gh < (unsigned)Hh) && wok; \
                stg[c][s] = inb                                                \
                    ? f1n[((size_t)((C0) + c) * Hh + gh) * Ww + gw]            \
                    : 0.f;                                                     \
            }                                                                  \
        }                                                                      \
    }

    LOAD_CHUNK(0);

    const int NCHUNK = Cc / CCH;   // 32
    for (int k = 0; k < NCHUNK; ++k) {
        __syncthreads();
        // staged regs -> LDS (XOR swizzle of 16B units by row&7)
#pragma unroll
        for (int c = 0; c < CCH; ++c) {
#pragma unroll
            for (int s = 0; s < 2; ++s) {
                const int r = srq + 24 * s;
                if (r < HR) {
                    const int u    = sj >> 2;
                    const int swzu = u ^ (r & 7);
                    lds[c][r][swzu * 4 + (sj & 3)] = stg[c][s];
                }
            }
        }
        __syncthreads();

        if (k + 1 < NCHUNK) LOAD_CHUNK((k + 1) * CCH);

        const int c0  = k * CCH;
        const int row = ty + wave;           // halo row this wave reads
#pragma unroll
        for (int cc = 0; cc < CCH; ++cc) {
            const float* fp = f0base + (size_t)(c0 + cc) * Hh * Ww;
            const float4 a0 = *reinterpret_cast<const float4*>(fp);
            const float4 a1 = *reinterpret_cast<const float4*>(fp + 4);
            const float a[PX] = {a0.x, a0.y, a0.z, a0.w, a1.x, a1.y, a1.z, a1.w};

            float wv[16];
#pragma unroll
            for (int i = 0; i < 4; ++i) {
                const int u = (2 * tx + i) ^ (row & 7);
                const float4 v =
                    reinterpret_cast<const float4*>(&lds[cc][row][0])[u];
                wv[4 * i + 0] = v.x;
                wv[4 * i + 1] = v.y;
                wv[4 * i + 2] = v.z;
                wv[4 * i + 3] = v.w;
            }
#pragma unroll
            for (int dx = 0; dx < DD; ++dx)
#pragma unroll
                for (int p = 0; p < PX; ++p)
                    acc[dx][p] += a[p] * wv[p + dx];
        }
    }

    // epilogue: write 72 outputs per thread (2x float4 per dx)
    const int hh  = h0 + ty;
    const int wwp = w0 + PX * tx;
#pragma unroll
    for (int dx = 0; dx < DD; ++dx) {
        const int d = wave * DD + dx;
        float* op = out + (((size_t)n * (DD * DD) + d) * Hh + hh) * Ww + wwp;
        const float4 o0 = make_float4(acc[dx][0], acc[dx][1], acc[dx][2], acc[dx][3]);
        const float4 o1 = make_float4(acc[dx][4], acc[dx][5], acc[dx][6], acc[dx][7]);
        *reinterpret_cast<float4*>(op)     = o0;
        *reinterpret_cast<float4*>(op + 4) = o1;
    }
}

extern "C" void kernel_launch(void* const* d_in, const int* in_sizes, int n_in,
                              void* d_out, int out_size, void* d_ws, size_t ws_size,
                              hipStream_t stream) {
    const float* f0 = (const float*)d_in[0];
    const float* f1 = (const float*)d_in[1];
    float* out = (float*)d_out;
    // grid: 8 n * 4 h-tiles * 8 w-tiles = 256 blocks, 576 threads
    corr_kernel<<<dim3(256), dim3(576), 0, stream>>>(f0, f1, out);
}